// Round 10
// baseline (1151.480 us; speedup 1.0000x reference)
//
#include <hip/hip_runtime.h>
#include <hip/hip_bf16.h>

// Problem constants
#define DM    1024
#define NH    2
#define IDX   32
#define HQ    (NH*IDX)
#define TT    4096
#define BB    2
#define RR    (BB*TT)
#define NC    112
#define NTIL  7
#define SCW   512
#define SCH   (TT/SCW)

// DIAGNOSTIC ROUND 2: paired A/B dispatches isolate per-phase costs.
// All reps write identical values (zoff==0) -> output exact. Keepalive
// asm prevents DCE of compute in store-skipping variants (rule #17).
#define REP_PREP  64
#define REP_PROJ  24
#define REP_SCORE 10

typedef short  s16x4 __attribute__((ext_vector_type(4)));
typedef short  s16x8 __attribute__((ext_vector_type(8)));
typedef float  f32x4 __attribute__((ext_vector_type(4)));

__device__ __forceinline__ unsigned short f2bf(float f) {
    __hip_bfloat16 h = __float2bfloat16(f);
    return __builtin_bit_cast(unsigned short, h);
}
__device__ __forceinline__ void keep4(f32x4 v) {
    asm volatile("" :: "v"(v[0]), "v"(v[1]), "v"(v[2]), "v"(v[3]));
}

// ---------------------------------------------------------------------------
// Kernel 1: pack Wq|Wk|Ww -> WcatT[NC][DM]  (rep-wrapped, stores are side
// effects so the loop cannot collapse)
// ---------------------------------------------------------------------------
__global__ __launch_bounds__(256) void prep_wcat(const float* __restrict__ Wq0,
                                                 const float* __restrict__ Wk0,
                                                 const float* __restrict__ Ww0,
                                                 unsigned short* __restrict__ WcatT0,
                                                 int reps, int zoff) {
    int idx = blockIdx.x * 256 + threadIdx.x;
    int j = idx >> 10;
    int i = idx & 1023;
    for (int rep = 0; rep < reps; ++rep) {
        const float* Wq = Wq0 + (rep & zoff);
        const float* Wk = Wk0 + (rep & zoff);
        const float* Ww = Ww0 + (rep & zoff);
        unsigned short* WcatT = WcatT0 + (rep & zoff);
        float v = 0.f;
        if (j < 64)       v = Wq[i * HQ + j];
        else if (j < 96)  v = Wk[i * IDX + (j - 64)];
        else if (j < 98)  v = Ww[i * NH + (j - 96)];
        WcatT[j * DM + i] = f2bf(v);
    }
}

// ---------------------------------------------------------------------------
// proj body (R9 LDS-staged structure), EPI_EVERY toggles whether the
// reduce+epilogue runs every rep or only on the final rep.
// ---------------------------------------------------------------------------
template<bool EPI_EVERY>
__device__ __forceinline__ void proj_body(const float* __restrict__ x0,
                                          const unsigned short* __restrict__ W0,
                                          unsigned short* __restrict__ Qb0,
                                          unsigned short* __restrict__ Kb0,
                                          float* __restrict__ wb0,
                                          int reps, int zoff,
                                          unsigned char* smem) {
    const int tid  = threadIdx.x;
    const int wave = tid >> 6;
    const int lane = tid & 63;
    const int r0   = blockIdx.x * 16;
    const int lrow = lane & 15;
    const int lseg = lane >> 4;

    for (int rep = 0; rep < reps; ++rep) {
        const float*          x     = x0 + (rep & zoff);
        const unsigned short* WcatT = W0 + (rep & zoff);
        unsigned short*       Qb    = Qb0 + (rep & zoff);
        unsigned short*       Kb    = Kb0 + (rep & zoff);
        float*                wb    = wb0 + (rep & zoff);

        // stage: contiguous x read -> swizzled bf16 LDS tile
        const float4* xsrc = (const float4*)(x + (size_t)r0 * DM);
        #pragma unroll 8
        for (int i = 0; i < 16; ++i) {
            float4 a = xsrc[i * 256 + tid];
            const int boff = i * 2048 + ((tid * 8) ^ ((i & 7) << 4));
            s16x4 h;
            h[0] = (short)f2bf(a.x); h[1] = (short)f2bf(a.y);
            h[2] = (short)f2bf(a.z); h[3] = (short)f2bf(a.w);
            *(s16x4*)(smem + boff) = h;
        }
        __syncthreads();

        // compute: wave = K-quarter, all 7 tiles
        f32x4 acc[NTIL] = {};
        const unsigned short* wr = WcatT + (size_t)lrow * DM + wave * 256 + lseg * 8;
        #pragma unroll
        for (int kc = 0; kc < 8; ++kc) {
            const int boff = lrow * 2048 +
                ((wave * 512 + kc * 64 + lseg * 16) ^ ((lrow & 7) << 4));
            s16x8 af = *(const s16x8*)(smem + boff);
            #pragma unroll
            for (int t = 0; t < NTIL; ++t) {
                s16x8 bfv = *(const s16x8*)(wr + (size_t)t * 16 * DM + kc * 32);
                acc[t] = __builtin_amdgcn_mfma_f32_16x16x32_bf16(af, bfv, acc[t], 0, 0, 0);
            }
        }
        __syncthreads();   // all waves done reading stage

        if (EPI_EVERY || rep == reps - 1) {
            float* red = (float*)smem;
            #pragma unroll
            for (int t = 0; t < NTIL; ++t)
                *(f32x4*)&red[(((wave * NTIL) + t) * 64 + lane) * 4] = acc[t];
            __syncthreads();
            #pragma unroll
            for (int u = 0; u < 2; ++u) {
                const int t = wave + u * 4;
                if (t >= NTIL) break;
                f32x4 s = *(const f32x4*)&red[((0 * NTIL + t) * 64 + lane) * 4];
                s += *(const f32x4*)&red[((1 * NTIL + t) * 64 + lane) * 4];
                s += *(const f32x4*)&red[((2 * NTIL + t) * 64 + lane) * 4];
                s += *(const f32x4*)&red[((3 * NTIL + t) * 64 + lane) * 4];
                const int col = t * 16 + lrow;
                #pragma unroll
                for (int r = 0; r < 4; ++r) {
                    int row = r0 + lseg * 4 + r;
                    float v = s[r];
                    if (col < 64)       Qb[(size_t)row * HQ + col]         = f2bf(v);
                    else if (col < 96)  Kb[(size_t)row * IDX + (col - 64)] = f2bf(v);
                    else if (col < 98)  wb[(size_t)row * NH + (col - 96)]  = v;
                }
            }
            __syncthreads();   // red WAR vs next rep's stage
        } else {
            #pragma unroll
            for (int t = 0; t < NTIL; ++t) keep4(acc[t]);
        }
    }
}

__global__ __launch_bounds__(256) void proj_full(const float* __restrict__ x,
                                                 const unsigned short* __restrict__ W,
                                                 unsigned short* __restrict__ Qb,
                                                 unsigned short* __restrict__ Kb,
                                                 float* __restrict__ wb,
                                                 int reps, int zoff) {
    __shared__ __align__(16) unsigned char smem[32768];
    proj_body<true>(x, W, Qb, Kb, wb, reps, zoff, smem);
}
__global__ __launch_bounds__(256) void proj_noepi(const float* __restrict__ x,
                                                  const unsigned short* __restrict__ W,
                                                  unsigned short* __restrict__ Qb,
                                                  unsigned short* __restrict__ Kb,
                                                  float* __restrict__ wb,
                                                  int reps, int zoff) {
    __shared__ __align__(16) unsigned char smem[32768];
    proj_body<false>(x, W, Qb, Kb, wb, reps, zoff, smem);
}

// ---------------------------------------------------------------------------
// score body (R5 structure), ST_EVERY toggles the global stores.
// ---------------------------------------------------------------------------
template<bool ST_EVERY>
__device__ __forceinline__ void score_body(const unsigned short* __restrict__ Qb0,
                                           const unsigned short* __restrict__ Kb0,
                                           const float* __restrict__ wb0,
                                           float* __restrict__ out0,
                                           int reps, int zoff) {
    const int rb   = blockIdx.x >> 3;
    const int sc   = blockIdx.x & (SCH - 1);
    const int wave = threadIdx.x >> 6;
    const int lane = threadIdx.x & 63;
    const int trow = lane & 15;
    const int lseg = lane >> 4;

    const int t0 = rb * 64 + wave * 16;
    const int b  = t0 >> 12;
    const int s0 = sc * SCW;
    const f32x4 zero = {0.f, 0.f, 0.f, 0.f};

    for (int rep = 0; rep < reps; ++rep) {
        const unsigned short* Qb  = Qb0 + (rep & zoff);
        const unsigned short* Kb  = Kb0 + (rep & zoff);
        const float*          wb  = wb0 + (rep & zoff);
        float*                out = out0 + (rep & zoff);

        const unsigned short* qrow = Qb + (size_t)(t0 + trow) * HQ + lseg * 8;
        s16x8 qb0 = *(const s16x8*)(qrow);
        s16x8 qb1 = *(const s16x8*)(qrow + IDX);
        float2 wt = *(const float2*)(wb + (size_t)(t0 + trow) * NH);

        const unsigned short* kbase =
            Kb + ((size_t)(b * TT) + s0 + trow) * IDX + lseg * 8;
        float* obase = out + (size_t)(t0 + trow) * TT + s0 + lseg * 4;

        const bool do_store = ST_EVERY || (rep == reps - 1);

        #pragma unroll 4
        for (int it = 0; it < SCW / 16; ++it) {
            s16x8 kb = *(const s16x8*)(kbase + (size_t)it * 16 * IDX);
            f32x4 d0 = __builtin_amdgcn_mfma_f32_16x16x32_bf16(kb, qb0, zero, 0, 0, 0);
            f32x4 d1 = __builtin_amdgcn_mfma_f32_16x16x32_bf16(kb, qb1, zero, 0, 0, 0);
            f32x4 v;
            #pragma unroll
            for (int r = 0; r < 4; ++r)
                v[r] = wt.x * fmaxf(d0[r], 0.f) + wt.y * fmaxf(d1[r], 0.f);
            if (do_store) *(f32x4*)(obase + it * 16) = v;
            else          keep4(v);
        }
    }
}

__global__ __launch_bounds__(256) void score_full(const unsigned short* __restrict__ Qb,
                                                  const unsigned short* __restrict__ Kb,
                                                  const float* __restrict__ wb,
                                                  float* __restrict__ out,
                                                  int reps, int zoff) {
    score_body<true>(Qb, Kb, wb, out, reps, zoff);
}
__global__ __launch_bounds__(256) void score_nost(const unsigned short* __restrict__ Qb,
                                                  const unsigned short* __restrict__ Kb,
                                                  const float* __restrict__ wb,
                                                  float* __restrict__ out,
                                                  int reps, int zoff) {
    score_body<false>(Qb, Kb, wb, out, reps, zoff);
}

// ---------------------------------------------------------------------------
extern "C" void kernel_launch(void* const* d_in, const int* in_sizes, int n_in,
                              void* d_out, int out_size, void* d_ws, size_t ws_size,
                              hipStream_t stream) {
    const float* x  = (const float*)d_in[0];
    const float* Wq = (const float*)d_in[1];
    const float* Wk = (const float*)d_in[2];
    const float* Ww = (const float*)d_in[3];
    float* out = (float*)d_out;

    char* ws = (char*)d_ws;
    unsigned short* WcatT = (unsigned short*)ws;
    unsigned short* Qb    = (unsigned short*)(ws + 256 * 1024);
    unsigned short* Kb    = (unsigned short*)(ws + 256 * 1024 + 1024 * 1024);
    float*          wb    = (float*)(ws + 256 * 1024 + 1024 * 1024 + 512 * 1024);

    hipLaunchKernelGGL(prep_wcat, dim3((NC * DM) / 256), dim3(256), 0, stream,
                       Wq, Wk, Ww, WcatT, REP_PREP, 0);
    hipLaunchKernelGGL(proj_full, dim3(RR / 16), dim3(256), 0, stream,
                       x, WcatT, Qb, Kb, wb, REP_PROJ, 0);
    hipLaunchKernelGGL(proj_noepi, dim3(RR / 16), dim3(256), 0, stream,
                       x, WcatT, Qb, Kb, wb, REP_PROJ, 0);
    hipLaunchKernelGGL(score_full, dim3((RR / 64) * SCH), dim3(256), 0, stream,
                       Qb, Kb, wb, out, REP_SCORE, 0);
    hipLaunchKernelGGL(score_nost, dim3((RR / 64) * SCH), dim3(256), 0, stream,
                       Qb, Kb, wb, out, REP_SCORE, 0);
}